// Round 7
// baseline (4732.734 us; speedup 1.0000x reference)
//
#include <hip/hip_runtime.h>
#include <hip/hip_bf16.h>
#include <stdint.h>

// ---------------- constants ----------------
#define TT 64
#define BB 32
#define NHIDC 768
#define NBK 6
#define BSZ 128
#define NTOKC 32000

using f32x4  = __attribute__((ext_vector_type(4))) float;
using f32x2  = __attribute__((ext_vector_type(2))) float;
using short8 = __attribute__((ext_vector_type(8))) short;

// ---------------- workspace layout (bytes) ----------------
#define OFF_FLG   0u           // [128] u32 flags
#define OFF_XPUB  4096u        // [2][16][6][2][132] f32 exchange (202,752 B)
#define OFF_HTB   8065024u     // [64][32][768] bf16
#define OFF_K1    11210752u    // [64][32][64] f32
#define OFF_V1    11735040u    // [64][32][512] f32
#define OFF_U     15929344u    // [64][32][6][512] f32
#define OFF_WDB   41095168u    // [32000][768] bf16

__device__ __forceinline__ float sigf(float x){ return 1.f/(1.f + expf(-x)); }

// fine-grained MALL-coherent scalar ops — used ONLY for the small per-step
// exchange (k2|v2|null publish + flags), never bulk data.
__device__ __forceinline__ void stc(float* p, float v){
  __hip_atomic_store(p, v, __ATOMIC_RELAXED, __HIP_MEMORY_SCOPE_AGENT);
}
__device__ __forceinline__ float ldc(const float* p){
  return __hip_atomic_load(p, __ATOMIC_RELAXED, __HIP_MEMORY_SCOPE_AGENT);
}
#define VMCNT0 asm volatile("s_waitcnt vmcnt(0)" ::: "memory")
#define CBAR   asm volatile("" ::: "memory")

__device__ __forceinline__ void gload16(const void* g, void* l){
  __builtin_amdgcn_global_load_lds(
      (const __attribute__((address_space(1))) unsigned int*)g,
      (__attribute__((address_space(3))) unsigned int*)l, 16, 0, 0);
}

__device__ __forceinline__ int xslot(int par, int gg, int nn, int b){
  return (((par*16 + gg)*6 + nn)*2 + b)*132;
}

// ---------------- prep: reset flags + cast Wd->bf16 ----------------
__global__ void prep_kernel(const float* __restrict__ Wd,
                            unsigned short* __restrict__ Wdb,
                            unsigned int* __restrict__ flags)
{
  if (blockIdx.x == 0 && threadIdx.x < 128)
    __hip_atomic_store(flags + threadIdx.x, 0u, __ATOMIC_RELAXED, __HIP_MEMORY_SCOPE_AGENT);
  int i = blockIdx.x*blockDim.x + threadIdx.x;
  const int n = NTOKC*NHIDC;
  const int stride = gridDim.x*blockDim.x;
  for (; i < n; i += stride){
    __hip_bfloat16 h = __float2bfloat16(Wd[i]);
    Wdb[i] = *reinterpret_cast<unsigned short*>(&h);
  }
}

// ---------------- generic f32 tiled GEMM: C = A @ B ----------------
template<int TM, int TN>
__global__ __launch_bounds__(256) void gemm_f32(
    const float* __restrict__ A, int lda,
    const float* __restrict__ B, int ldb, long bstride,
    float* __restrict__ C, int ldc, long cstride,
    int N, int K)
{
  constexpr int BM = 16*TM, BN = 16*TN;
  __shared__ float As[16][BM];
  __shared__ float Bs[16][BN+4];
  const float* Bb = B + (long)blockIdx.z * bstride;
  float* Cb = C + (long)blockIdx.z * cstride;
  const int m0 = blockIdx.x*BM, n0 = blockIdx.y*BN;
  const int tid = threadIdx.x, tx = tid & 15, ty = tid >> 4;
  float acc[TM][TN];
  #pragma unroll
  for (int i=0;i<TM;++i)
    #pragma unroll
    for (int j=0;j<TN;++j) acc[i][j]=0.f;

  for (int k0=0; k0<K; k0+=16){
    if constexpr (TM == 8){
      const int r = tid>>1, kk = (tid&1)*8;
      const float4 v0 = *(const float4*)&A[(long)(m0+r)*lda + k0 + kk];
      const float4 v1 = *(const float4*)&A[(long)(m0+r)*lda + k0 + kk + 4];
      As[kk+0][r]=v0.x; As[kk+1][r]=v0.y; As[kk+2][r]=v0.z; As[kk+3][r]=v0.w;
      As[kk+4][r]=v1.x; As[kk+5][r]=v1.y; As[kk+6][r]=v1.z; As[kk+7][r]=v1.w;
    } else {
      const int r = tid>>2, kk = (tid&3)*4;
      const float4 v0 = *(const float4*)&A[(long)(m0+r)*lda + k0 + kk];
      As[kk+0][r]=v0.x; As[kk+1][r]=v0.y; As[kk+2][r]=v0.z; As[kk+3][r]=v0.w;
    }
    if constexpr (TN == 8){
      const int rb = tid>>4, cb = (tid&15)*8;
      float4 v0 = {0,0,0,0}, v1 = {0,0,0,0};
      if (n0+cb+4 <= N) v0 = *(const float4*)&Bb[(long)(k0+rb)*ldb + n0+cb];
      if (n0+cb+8 <= N) v1 = *(const float4*)&Bb[(long)(k0+rb)*ldb + n0+cb+4];
      *(float4*)&Bs[rb][cb]   = v0;
      *(float4*)&Bs[rb][cb+4] = v1;
    } else {
      const int rb = tid>>4, cb = (tid&15)*4;
      float4 v0 = {0,0,0,0};
      if (n0+cb+4 <= N) v0 = *(const float4*)&Bb[(long)(k0+rb)*ldb + n0+cb];
      *(float4*)&Bs[rb][cb] = v0;
    }
    __syncthreads();
    #pragma unroll
    for (int kk=0; kk<16; ++kk){
      float av[TM], bv[TN];
      #pragma unroll
      for (int i=0;i<TM;++i) av[i] = As[kk][ty*TM+i];
      #pragma unroll
      for (int j=0;j<TN;++j) bv[j] = Bs[kk][tx*TN+j];
      #pragma unroll
      for (int i=0;i<TM;++i)
        #pragma unroll
        for (int j=0;j<TN;++j) acc[i][j] += av[i]*bv[j];
    }
    __syncthreads();
  }
  #pragma unroll
  for (int i=0;i<TM;++i){
    const int row = m0 + ty*TM + i;
    #pragma unroll
    for (int j=0;j<TN;++j){
      const int col = n0 + tx*TN + j;
      if (col < N) Cb[(long)row*ldc + col] = acc[i][j];
    }
  }
}

// ---------------- persistent recurrent kernel ----------------
// 96 WGs x 512 threads. WG w: group gg = w/6 (batches 2gg, 2gg+1), block n = w%6.
// Everything is WG-local except one per-step exchange of {k2, v2, null}
// (129 floats per (batch, block)) among the 6 WGs of a group, via MALL-coherent
// scalar atomics + one flag round (own-flag store, poll 6).
__global__ __launch_bounds__(512, 2) void recurrent_kernel(
    const float* __restrict__ hx0, const float* __restrict__ cx0,
    const float* __restrict__ Wq_in, const float* __restrict__ Whh,
    const float* __restrict__ b_lstm,
    const float* __restrict__ Wk_c, const float* __restrict__ Wv_c,
    const float* __restrict__ Wq_c, const float* __restrict__ Wo_c,
    const float* __restrict__ K1buf, const float* __restrict__ Ubuf,
    float* __restrict__ xpub, unsigned int* __restrict__ flags,
    unsigned short* __restrict__ HTx,
    float* __restrict__ out_hx, float* __restrict__ out_cx)
{
  const int w = blockIdx.x, gg = w/6, n = w - gg*6, tid = threadIdx.x;

  __shared__ float WcT[192*130];        // [c][h], c: 0-63 k2, 64-127 v2, 128-191 q2
  __shared__ float hL[2][128], cL[2][128], h0L[2][128], cnL[2][128];
  __shared__ float gatesL[2][512];
  __shared__ float kvqL[2][192];
  __shared__ float kvAll[2][6][130];
  __shared__ float attL[2][4][6], attW[2][4][6];
  __shared__ float commL[2][64];
  __shared__ float nullAll[2][6], sL[2], nullLoc[2], maskL[2];

  // ---- weights: Whh column-per-thread in registers; Wo 16/thread ----
  float whr[128];
  #pragma unroll
  for (int h=0; h<128; ++h) whr[h] = Whh[(long)n*65536 + h*512 + tid];
  float wor[16];
  {
    const int d = tid>>2, kq = tid&3;
    #pragma unroll
    for (int j=0;j<16;++j) wor[j] = Wo_c[n*8192 + (kq*16+j)*128 + d];
  }
  const float blr = b_lstm[n*512 + tid];
  for (int i = tid; i < 8192; i += 512){
    const int h = i>>6, c = i&63;
    WcT[(c    )*130 + h] = Wk_c[n*8192 + i];
    WcT[(c+ 64)*130 + h] = Wv_c[n*8192 + i];
    WcT[(c+128)*130 + h] = Wq_c[n*8192 + i];
  }
  if (tid < 256){
    const int b = tid>>7, d = tid&127;
    hL[b][d] = hx0[(gg*2+b)*768 + n*128 + d];
    cL[b][d] = cx0[(gg*2+b)*768 + n*128 + d];
  }
  __syncthreads();

  const float* wq = Wq_in + n*8192;

  for (int t = 0; t < TT; ++t){
    const int par = t & 1;
    // prefetch U (own gate col, both batches) + K1
    const float u0 = Ubuf[((long)(t*32 + gg*2+0)*6 + n)*512 + tid];
    const float u1 = Ubuf[((long)(t*32 + gg*2+1)*6 + n)*512 + tid];
    float k1r = 0.f;
    if (tid < 128) k1r = K1buf[(long)(t*32 + gg*2 + (tid>>6))*64 + (tid&63)];

    // A: gates dot (thread = gate col), h broadcast from LDS
    float gd0 = 0.f, gd1 = 0.f;
    #pragma unroll
    for (int h4 = 0; h4 < 32; ++h4){
      const f32x4 h0v = *(const f32x4*)&hL[0][h4*4];
      const f32x4 h1v = *(const f32x4*)&hL[1][h4*4];
      #pragma unroll
      for (int j=0;j<4;++j){
        gd0 += whr[h4*4+j]*h0v[j];
        gd1 += whr[h4*4+j]*h1v[j];
      }
    }
    // B: q1 + input-softmax s (tid<128; wave b)
    if (tid < 128){
      const int b = tid>>6, k = tid&63;
      float q = 0.f;
      #pragma unroll 16
      for (int h=0; h<128; ++h) q += wq[h*64 + k]*hL[b][h];
      float term = q*k1r;
      #pragma unroll
      for (int off=32; off; off>>=1) term += __shfl_xor(term, off);
      if (k == 0){
        const float l1 = term*0.125f;
        const float mx = fmaxf(l1, 0.f);
        const float e0 = expf(0.f-mx), e1 = expf(l1-mx);
        const float inv = 1.f/(e0+e1);
        sL[b] = e1*inv; nullLoc[b] = e0*inv;
      }
    }
    __syncthreads();                                     // (1)
    // D: finalize gates with s*U + bias
    gatesL[0][tid] = gd0 + sL[0]*u0 + blr;
    gatesL[1][tid] = gd1 + sL[1]*u1 + blr;
    __syncthreads();                                     // (2)
    // F: pointwise LSTM
    if (tid < 256){
      const int b = tid>>7, dd = tid&127;
      const float gi = gatesL[b][dd],     gf = gatesL[b][128+dd];
      const float gG = gatesL[b][256+dd], go = gatesL[b][384+dd];
      const float cp = cL[b][dd];
      const float cn = sigf(gf)*cp + sigf(gi)*tanhf(gG);
      const float h0 = sigf(go)*tanhf(cn);
      cnL[b][dd] = cn; h0L[b][dd] = h0;
    }
    __syncthreads();                                     // (3)
    // H: k2|v2|q2 = h0 @ Wc (thread = col c of 192)
    if (tid < 192){
      const int c = tid;
      float a0 = 0.f, a1 = 0.f;
      #pragma unroll
      for (int h4=0; h4<32; ++h4){
        const f32x2 wa = *(const f32x2*)&WcT[c*130 + h4*4];
        const f32x2 wb = *(const f32x2*)&WcT[c*130 + h4*4 + 2];
        const f32x4 h0v = *(const f32x4*)&h0L[0][h4*4];
        const f32x4 h1v = *(const f32x4*)&h0L[1][h4*4];
        a0 += wa[0]*h0v[0] + wa[1]*h0v[1] + wb[0]*h0v[2] + wb[1]*h0v[3];
        a1 += wa[0]*h1v[0] + wa[1]*h1v[1] + wb[0]*h1v[2] + wb[1]*h1v[3];
      }
      kvqL[0][c] = a0; kvqL[1][c] = a1;
    }
    __syncthreads();                                     // (4)
    // J: publish k2|v2 (128 f) + null per batch
    if (tid < 256){
      const int b = tid>>7, idx = tid&127;
      stc(&xpub[xslot(par,gg,n,b) + idx], kvqL[b][idx]);
    }
    if (tid < 2) stc(&xpub[xslot(par,gg,n,tid) + 128], nullLoc[tid]);
    VMCNT0;
    __syncthreads();                                     // (5)
    if (tid < 6){
      if (tid == 0)
        __hip_atomic_store(&flags[gg*8+n], (unsigned)(t+1), __ATOMIC_RELAXED, __HIP_MEMORY_SCOPE_AGENT);
      while (__hip_atomic_load(&flags[gg*8+tid], __ATOMIC_RELAXED, __HIP_MEMORY_SCOPE_AGENT) < (unsigned)(t+1))
        __builtin_amdgcn_s_sleep(1);
    }
    __syncthreads(); CBAR;                               // (6)
    // L: stage all 6 blocks' k2/v2 + nulls into LDS
    for (int idx = tid; idx < 1536; idx += 512){
      const int j = idx/256, r = idx&255, b = r>>7, c = r&127;
      kvAll[b][j][c] = ldc(&xpub[xslot(par,gg,j,b) + c]);
    }
    if (tid < 12){
      const int j = tid>>1, b = tid&1;
      nullAll[b][j] = ldc(&xpub[xslot(par,gg,j,b) + 128]);
    }
    __syncthreads();                                     // (7)
    // N: att logits (i = n) + mask ranks
    if (tid < 48){
      const int b = tid/24, h = (tid/6)%4, j = tid%6;
      float lg = 0.f;
      #pragma unroll
      for (int kk=0; kk<16; ++kk)
        lg += kvqL[b][128 + h*16 + kk]*kvAll[b][j][h*16 + kk];
      attL[b][h][j] = lg*0.25f;
    }
    if (tid >= 48 && tid < 50){
      const int b = tid - 48;
      const float own = nullAll[b][n];
      int rank = 0;
      #pragma unroll
      for (int j=0;j<6;++j){
        const float v = nullAll[b][j];
        rank += (v > own || (v == own && j < n)) ? 1 : 0;
      }
      maskL[b] = (rank < 2) ? 0.f : 1.f;
    }
    __syncthreads();                                     // (8)
    if (tid < 8){
      const int b = tid>>2, h = tid&3;
      float mx = attL[b][h][0];
      #pragma unroll
      for (int j=1;j<6;++j) mx = fmaxf(mx, attL[b][h][j]);
      float e[6], sum = 0.f;
      #pragma unroll
      for (int j=0;j<6;++j){ e[j] = expf(attL[b][h][j]-mx); sum += e[j]; }
      const float inv = 1.f/sum;
      #pragma unroll
      for (int j=0;j<6;++j) attW[b][h][j] = e[j]*inv;
    }
    __syncthreads();                                     // (9)
    if (tid < 128){
      const int b = tid>>6, hv = tid&63, h = hv>>4, v = hv&15;
      float s2 = 0.f;
      #pragma unroll
      for (int j=0;j<6;++j) s2 += attW[b][h][j]*kvAll[b][j][64 + h*16 + v];
      commL[b][hv] = s2;
    }
    __syncthreads();                                     // (10)
    // Q: Wo + masked state update
    {
      const int d = tid>>2, kq = tid&3;
      float a0 = 0.f, a1 = 0.f;
      #pragma unroll
      for (int j=0;j<16;++j){
        a0 += commL[0][kq*16+j]*wor[j];
        a1 += commL[1][kq*16+j]*wor[j];
      }
      a0 += __shfl_xor(a0,1); a0 += __shfl_xor(a0,2);
      a1 += __shfl_xor(a1,1); a1 += __shfl_xor(a1,2);
      if (kq == 0){
        if (maskL[0] != 0.f){ hL[0][d] = h0L[0][d] + a0; cL[0][d] = cnL[0][d]; }
        if (maskL[1] != 0.f){ hL[1][d] = h0L[1][d] + a1; cL[1][d] = cnL[1][d]; }
      }
    }
    __syncthreads();                                     // (11)
    // R: HT (bf16) + final outputs
    if (tid < 256){
      const int b = tid>>7, d = tid&127;
      const float hv = hL[b][d];
      __hip_bfloat16 hb16 = __float2bfloat16(hv);
      HTx[(long)(t*32 + gg*2 + b)*768 + n*128 + d] = *reinterpret_cast<unsigned short*>(&hb16);
      if (t == TT-1){
        out_hx[(gg*2+b)*768 + n*128 + d] = hv;
        out_cx[(gg*2+b)*768 + n*128 + d] = cL[b][d];
      }
    }
  }
}

// ---------------- decoder: out = HT @ Wd^T + bd, bf16 MFMA ----------------
__global__ __launch_bounds__(256) void decoder_kernel(
    const unsigned short* __restrict__ A,   // [2048][768] bf16
    const unsigned short* __restrict__ Bw,  // [32000][768] bf16
    const float* __restrict__ bd,
    float* __restrict__ out)
{
  __shared__ unsigned short As[4096];  // [128][32]
  __shared__ unsigned short Bs[4096];  // [128][32]
  const int m0 = blockIdx.x*128, n0 = blockIdx.y*128;
  const int tid = threadIdx.x;
  const int wv = tid >> 6, lane = tid & 63;
  const int wm = wv >> 1, wn = wv & 1;
  const int r16 = lane & 15, krow = lane >> 4;

  f32x4 acc[4][4] = {};

  for (int k0 = 0; k0 < 768; k0 += 32){
    #pragma unroll
    for (int i=0; i<2; ++i){
      const int idx = i*256 + tid;
      const int row = idx >> 2, k8 = (idx & 3)*8;
      gload16(&A [(long)(m0+row)*768 + k0 + k8], (char*)As + i*4096 + wv*1024);
      gload16(&Bw[(long)(n0+row)*768 + k0 + k8], (char*)Bs + i*4096 + wv*1024);
    }
    __syncthreads();
    short8 af[4], bf[4];
    #pragma unroll
    for (int mi=0; mi<4; ++mi)
      af[mi] = *(const short8*)&As[(wm*64 + mi*16 + r16)*32 + krow*8];
    #pragma unroll
    for (int ni=0; ni<4; ++ni)
      bf[ni] = *(const short8*)&Bs[(wn*64 + ni*16 + r16)*32 + krow*8];
    #pragma unroll
    for (int mi=0; mi<4; ++mi)
      #pragma unroll
      for (int ni=0; ni<4; ++ni)
        acc[mi][ni] = __builtin_amdgcn_mfma_f32_16x16x32_bf16(af[mi], bf[ni], acc[mi][ni], 0, 0, 0);
    __syncthreads();
  }

  #pragma unroll
  for (int ni=0; ni<4; ++ni){
    const int col = n0 + wn*64 + ni*16 + r16;
    const float bv = bd[col];
    #pragma unroll
    for (int mi=0; mi<4; ++mi){
      const int rbase = m0 + wm*64 + mi*16 + krow*4;
      #pragma unroll
      for (int j=0; j<4; ++j)
        out[(size_t)(rbase + j)*NTOKC + col] = acc[mi][ni][j] + bv;
    }
  }
}

// ---------------- launch ----------------
extern "C" void kernel_launch(void* const* d_in, const int* in_sizes, int n_in,
                              void* d_out, int out_size, void* d_ws, size_t ws_size,
                              hipStream_t stream)
{
  (void)in_sizes; (void)n_in; (void)out_size; (void)ws_size;
  const float* x      = (const float*)d_in[0];
  const float* hx0    = (const float*)d_in[1];
  const float* cx0    = (const float*)d_in[2];
  const float* Wq_in  = (const float*)d_in[3];
  const float* Wk_in  = (const float*)d_in[4];
  const float* Wv_in  = (const float*)d_in[5];
  const float* Wih    = (const float*)d_in[6];
  const float* Whh    = (const float*)d_in[7];
  const float* b_lstm = (const float*)d_in[8];
  const float* Wq_c   = (const float*)d_in[9];
  const float* Wk_c   = (const float*)d_in[10];
  const float* Wv_c   = (const float*)d_in[11];
  const float* Wo_c   = (const float*)d_in[12];
  const float* Wd     = (const float*)d_in[13];
  const float* bd     = (const float*)d_in[14];

  char* ws = (char*)d_ws;
  unsigned int*  flg  = (unsigned int*)(ws + OFF_FLG);
  float*         xpub = (float*)(ws + OFF_XPUB);
  unsigned short* HTx = (unsigned short*)(ws + OFF_HTB);
  float*         K1b  = (float*)(ws + OFF_K1);
  float*         V1b  = (float*)(ws + OFF_V1);
  float*         Ub   = (float*)(ws + OFF_U);
  unsigned short* Wdb = (unsigned short*)(ws + OFF_WDB);

  float* out_dec = (float*)d_out;
  float* out_hx  = out_dec + (size_t)2048*NTOKC;
  float* out_cx  = out_hx + BB*NHIDC;

  // 1) reset flags + Wd -> bf16
  prep_kernel<<<2048, 256, 0, stream>>>(Wd, Wdb, flg);
  // 2) K1 = x @ Wk_in[1]   (2048 x 64, K=768)
  gemm_f32<4,4><<<dim3(32,1,1), 256, 0, stream>>>(x, NHIDC, Wk_in + 768*64, 64, 0,
                                                  K1b, 64, 0, 64, NHIDC);
  // 3) V1 = x @ Wv_in[1]   (2048 x 512, K=768)
  gemm_f32<4,4><<<dim3(32,8,1), 256, 0, stream>>>(x, NHIDC, Wv_in + 768*512, 512, 0,
                                                  V1b, 512, 0, 512, NHIDC);
  // 4) U[:, n, :] = V1 @ Wih[n]  (2048 x 512 per n, K=512)
  gemm_f32<8,8><<<dim3(16,4,6), 256, 0, stream>>>(V1b, 512, Wih, 512, (long)512*512,
                                                  Ub, 3072, 512, 512, 512);
  // 5) recurrence: 96 WGs (16 groups x 6 blocks), writes HTx bf16 directly
  recurrent_kernel<<<96, 512, 0, stream>>>(hx0, cx0, Wq_in, Whh, b_lstm,
                                           Wk_c, Wv_c, Wq_c, Wo_c,
                                           K1b, Ub, xpub, flg, HTx,
                                           out_hx, out_cx);
  // 6) decoder GEMM + bias
  decoder_kernel<<<dim3(16,250,1), 256, 0, stream>>>(HTx, Wdb, bd, out_dec);
}

// Round 8
// 1259.281 us; speedup vs baseline: 3.7583x; 3.7583x over previous
//
#include <hip/hip_runtime.h>
#include <hip/hip_bf16.h>
#include <stdint.h>

// ---------------- constants ----------------
#define TT 64
#define BB 32
#define NHIDC 768
#define NBK 6
#define BSZ 128
#define NTOKC 32000

using f32x4  = __attribute__((ext_vector_type(4))) float;
using f32x2  = __attribute__((ext_vector_type(2))) float;
using short8 = __attribute__((ext_vector_type(8))) short;

// ---------------- workspace layout (bytes) ----------------
#define OFF_FLG   0u           // [128] u32 flags
#define OFF_XPUB  4096u        // [2][16][6][2][132] f32 exchange (202,752 B)
#define OFF_HTB   8065024u     // [64][32][768] bf16
#define OFF_K1    11210752u    // [64][32][64] f32
#define OFF_V1    11735040u    // [64][32][512] f32
#define OFF_U     15929344u    // [64][32][6][512] f32
#define OFF_WDB   41095168u    // [32000][768] bf16

__device__ __forceinline__ float sigf(float x){ return 1.f/(1.f + expf(-x)); }

// fine-grained MALL-coherent scalar ops — used ONLY for the small per-step
// exchange (k2|v2|null publish + flags), never bulk data.
__device__ __forceinline__ void stc(float* p, float v){
  __hip_atomic_store(p, v, __ATOMIC_RELAXED, __HIP_MEMORY_SCOPE_AGENT);
}
__device__ __forceinline__ float ldc(const float* p){
  return __hip_atomic_load(p, __ATOMIC_RELAXED, __HIP_MEMORY_SCOPE_AGENT);
}
#define VMCNT0 asm volatile("s_waitcnt vmcnt(0)" ::: "memory")
#define CBAR   asm volatile("" ::: "memory")

__device__ __forceinline__ void gload16(const void* g, void* l){
  __builtin_amdgcn_global_load_lds(
      (const __attribute__((address_space(1))) unsigned int*)g,
      (__attribute__((address_space(3))) unsigned int*)l, 16, 0, 0);
}

__device__ __forceinline__ int xslot(int par, int gg, int nn, int b){
  return (((par*16 + gg)*6 + nn)*2 + b)*132;
}

// ---------------- prep: reset flags + cast Wd->bf16 ----------------
__global__ void prep_kernel(const float* __restrict__ Wd,
                            unsigned short* __restrict__ Wdb,
                            unsigned int* __restrict__ flags)
{
  if (blockIdx.x == 0 && threadIdx.x < 128)
    __hip_atomic_store(flags + threadIdx.x, 0u, __ATOMIC_RELAXED, __HIP_MEMORY_SCOPE_AGENT);
  int i = blockIdx.x*blockDim.x + threadIdx.x;
  const int n = NTOKC*NHIDC;
  const int stride = gridDim.x*blockDim.x;
  for (; i < n; i += stride){
    __hip_bfloat16 h = __float2bfloat16(Wd[i]);
    Wdb[i] = *reinterpret_cast<unsigned short*>(&h);
  }
}

// ---------------- generic f32 tiled GEMM: C = A @ B ----------------
template<int TM, int TN>
__global__ __launch_bounds__(256) void gemm_f32(
    const float* __restrict__ A, int lda,
    const float* __restrict__ B, int ldb, long bstride,
    float* __restrict__ C, int ldc, long cstride,
    int N, int K)
{
  constexpr int BM = 16*TM, BN = 16*TN;
  __shared__ float As[16][BM];
  __shared__ float Bs[16][BN+4];
  const float* Bb = B + (long)blockIdx.z * bstride;
  float* Cb = C + (long)blockIdx.z * cstride;
  const int m0 = blockIdx.x*BM, n0 = blockIdx.y*BN;
  const int tid = threadIdx.x, tx = tid & 15, ty = tid >> 4;
  float acc[TM][TN];
  #pragma unroll
  for (int i=0;i<TM;++i)
    #pragma unroll
    for (int j=0;j<TN;++j) acc[i][j]=0.f;

  for (int k0=0; k0<K; k0+=16){
    if constexpr (TM == 8){
      const int r = tid>>1, kk = (tid&1)*8;
      const float4 v0 = *(const float4*)&A[(long)(m0+r)*lda + k0 + kk];
      const float4 v1 = *(const float4*)&A[(long)(m0+r)*lda + k0 + kk + 4];
      As[kk+0][r]=v0.x; As[kk+1][r]=v0.y; As[kk+2][r]=v0.z; As[kk+3][r]=v0.w;
      As[kk+4][r]=v1.x; As[kk+5][r]=v1.y; As[kk+6][r]=v1.z; As[kk+7][r]=v1.w;
    } else {
      const int r = tid>>2, kk = (tid&3)*4;
      const float4 v0 = *(const float4*)&A[(long)(m0+r)*lda + k0 + kk];
      As[kk+0][r]=v0.x; As[kk+1][r]=v0.y; As[kk+2][r]=v0.z; As[kk+3][r]=v0.w;
    }
    if constexpr (TN == 8){
      const int rb = tid>>4, cb = (tid&15)*8;
      float4 v0 = {0,0,0,0}, v1 = {0,0,0,0};
      if (n0+cb+4 <= N) v0 = *(const float4*)&Bb[(long)(k0+rb)*ldb + n0+cb];
      if (n0+cb+8 <= N) v1 = *(const float4*)&Bb[(long)(k0+rb)*ldb + n0+cb+4];
      *(float4*)&Bs[rb][cb]   = v0;
      *(float4*)&Bs[rb][cb+4] = v1;
    } else {
      const int rb = tid>>4, cb = (tid&15)*4;
      float4 v0 = {0,0,0,0};
      if (n0+cb+4 <= N) v0 = *(const float4*)&Bb[(long)(k0+rb)*ldb + n0+cb];
      *(float4*)&Bs[rb][cb] = v0;
    }
    __syncthreads();
    #pragma unroll
    for (int kk=0; kk<16; ++kk){
      float av[TM], bv[TN];
      #pragma unroll
      for (int i=0;i<TM;++i) av[i] = As[kk][ty*TM+i];
      #pragma unroll
      for (int j=0;j<TN;++j) bv[j] = Bs[kk][tx*TN+j];
      #pragma unroll
      for (int i=0;i<TM;++i)
        #pragma unroll
        for (int j=0;j<TN;++j) acc[i][j] += av[i]*bv[j];
    }
    __syncthreads();
  }
  #pragma unroll
  for (int i=0;i<TM;++i){
    const int row = m0 + ty*TM + i;
    #pragma unroll
    for (int j=0;j<TN;++j){
      const int col = n0 + tx*TN + j;
      if (col < N) Cb[(long)row*ldc + col] = acc[i][j];
    }
  }
}

// ---------------- persistent recurrent kernel ----------------
// 96 WGs x 1024 threads. WG w: group gg = w/6 (batches 2gg, 2gg+1), block n = w%6.
// Whh held in registers at 64 floats/thread (16 pinned f32x4) — fits under the
// 128-VGPR/16-wave budget so the compiler cannot profitably sink the loads
// (the R7 failure: 128 f/thread -> sunk -> 810 MB/dispatch HBM refetch).
// Wq_in staged in LDS. One cross-WG exchange round per step (flags + 258 f).
__global__ __launch_bounds__(1024, 2) void recurrent_kernel(
    const float* __restrict__ hx0, const float* __restrict__ cx0,
    const float* __restrict__ Wq_in, const float* __restrict__ Whh,
    const float* __restrict__ b_lstm,
    const float* __restrict__ Wk_c, const float* __restrict__ Wv_c,
    const float* __restrict__ Wq_c, const float* __restrict__ Wo_c,
    const float* __restrict__ K1buf, const float* __restrict__ Ubuf,
    float* __restrict__ xpub, unsigned int* __restrict__ flags,
    unsigned short* __restrict__ HTx,
    float* __restrict__ out_hx, float* __restrict__ out_cx)
{
  const int w = blockIdx.x, gg = w/6, n = w - gg*6, tid = threadIdx.x;

  __shared__ float WcT[192*130];        // [c][h] transposed, c: k2|v2|q2
  __shared__ float WqL[128*65];         // [h][k] padded
  __shared__ float hL[2][128], cL[2][128], h0L[2][128], cnL[2][128];
  __shared__ float gatesL[2][512];
  __shared__ float partL[2][2][512];    // [b][kh][c] gate partials
  __shared__ float kvqL[2][192];
  __shared__ float kvAll[2][6][130];
  __shared__ float attL[2][4][6], attW[2][4][6];
  __shared__ float commL[2][64];
  __shared__ float nullAll[2][6], sL[2], nullLoc[2], maskL[2];

  const int kh = tid >> 9, gc = tid & 511;   // gates: k-half, column
  const int od = tid >> 3, okq = tid & 7;    // Wo mapping

  // ---- Whh slice: 64 floats/thread, loaded once, pinned ----
  f32x4 whr[16];
  {
    const float* src = Whh + (long)n*65536 + kh*64*512 + gc;
    #pragma unroll
    for (int r4=0; r4<16; ++r4){
      f32x4 v;
      v[0] = src[(r4*4+0)*512]; v[1] = src[(r4*4+1)*512];
      v[2] = src[(r4*4+2)*512]; v[3] = src[(r4*4+3)*512];
      whr[r4] = v;
    }
  }
  #pragma unroll
  for (int i=0;i<16;++i) asm volatile("" : "+v"(whr[i]));
  // ---- Wo: 8 floats/thread, pinned ----
  f32x4 wo0, wo1;
  {
    const float* src = Wo_c + n*8192 + od;
    #pragma unroll
    for (int j=0;j<4;++j) wo0[j] = src[(okq*8+j)*128];
    #pragma unroll
    for (int j=0;j<4;++j) wo1[j] = src[(okq*8+4+j)*128];
  }
  asm volatile("" : "+v"(wo0));
  asm volatile("" : "+v"(wo1));
  const float blr = b_lstm[n*512 + gc];

  for (int i = tid; i < 8192; i += 1024){
    const int h = i>>6, c = i&63;
    WcT[(c    )*130 + h] = Wk_c[n*8192 + i];
    WcT[(c+ 64)*130 + h] = Wv_c[n*8192 + i];
    WcT[(c+128)*130 + h] = Wq_c[n*8192 + i];
    WqL[h*65 + c] = Wq_in[n*8192 + i];
  }
  if (tid < 256){
    const int b = tid>>7, d = tid&127;
    hL[b][d] = hx0[(gg*2+b)*768 + n*128 + d];
    cL[b][d] = cx0[(gg*2+b)*768 + n*128 + d];
  }
  __syncthreads();

  for (int t = 0; t < TT; ++t){
    const int par = t & 1;
    // prefetch U (own gate col, both batches, kh==0 waves only) + K1
    float u0 = 0.f, u1 = 0.f, k1r = 0.f;
    if (kh == 0){
      u0 = Ubuf[((long)(t*32 + gg*2+0)*6 + n)*512 + gc];
      u1 = Ubuf[((long)(t*32 + gg*2+1)*6 + n)*512 + gc];
    }
    if (tid < 128) k1r = K1buf[(long)(t*32 + gg*2 + (tid>>6))*64 + (tid&63)];

    // A: gate partials (thread = (kh, col)), h broadcast from LDS
    {
      float gd0 = 0.f, gd1 = 0.f;
      #pragma unroll
      for (int r4 = 0; r4 < 16; ++r4){
        const f32x4 h0v = *(const f32x4*)&hL[0][kh*64 + r4*4];
        const f32x4 h1v = *(const f32x4*)&hL[1][kh*64 + r4*4];
        #pragma unroll
        for (int j=0;j<4;++j){
          gd0 += whr[r4][j]*h0v[j];
          gd1 += whr[r4][j]*h1v[j];
        }
      }
      partL[0][kh][gc] = gd0;
      partL[1][kh][gc] = gd1;
    }
    // B: q1 + input-softmax s (tid<128; wave b), Wq from LDS
    if (tid < 128){
      const int b = tid>>6, k = tid&63;
      float q = 0.f;
      #pragma unroll 16
      for (int h=0; h<128; ++h) q += WqL[h*65 + k]*hL[b][h];
      float term = q*k1r;
      #pragma unroll
      for (int off=32; off; off>>=1) term += __shfl_xor(term, off);
      if (k == 0){
        const float l1 = term*0.125f;
        const float mx = fmaxf(l1, 0.f);
        const float e0 = expf(0.f-mx), e1 = expf(l1-mx);
        const float inv = 1.f/(e0+e1);
        sL[b] = e1*inv; nullLoc[b] = e0*inv;
      }
    }
    __syncthreads();                                     // (1)
    // D: combine partials + s*U + bias
    if (kh == 0){
      gatesL[0][gc] = partL[0][0][gc] + partL[0][1][gc] + sL[0]*u0 + blr;
      gatesL[1][gc] = partL[1][0][gc] + partL[1][1][gc] + sL[1]*u1 + blr;
    }
    __syncthreads();                                     // (2)
    // F: pointwise LSTM
    if (tid < 256){
      const int b = tid>>7, dd = tid&127;
      const float gi = gatesL[b][dd],     gf = gatesL[b][128+dd];
      const float gG = gatesL[b][256+dd], go = gatesL[b][384+dd];
      const float cp = cL[b][dd];
      const float cn = sigf(gf)*cp + sigf(gi)*tanhf(gG);
      const float h0 = sigf(go)*tanhf(cn);
      cnL[b][dd] = cn; h0L[b][dd] = h0;
    }
    __syncthreads();                                     // (3)
    // H: k2|v2|q2 = h0 @ Wc (thread = (b, col c of 192))
    if (tid < 384){
      const int b = tid/192, c = tid%192;
      float a = 0.f;
      #pragma unroll
      for (int h4=0; h4<32; ++h4){
        const f32x2 wa = *(const f32x2*)&WcT[c*130 + h4*4];
        const f32x2 wb = *(const f32x2*)&WcT[c*130 + h4*4 + 2];
        const f32x4 hv = *(const f32x4*)&h0L[b][h4*4];
        a += wa[0]*hv[0] + wa[1]*hv[1] + wb[0]*hv[2] + wb[1]*hv[3];
      }
      kvqL[b][c] = a;
    }
    __syncthreads();                                     // (4)
    // J: publish k2|v2 (128 f) + null per batch
    if (tid < 256){
      const int b = tid>>7, idx = tid&127;
      stc(&xpub[xslot(par,gg,n,b) + idx], kvqL[b][idx]);
    }
    if (tid < 2) stc(&xpub[xslot(par,gg,n,tid) + 128], nullLoc[tid]);
    VMCNT0;
    __syncthreads();                                     // (5)
    if (tid < 6){
      if (tid == 0)
        __hip_atomic_store(&flags[gg*8+n], (unsigned)(t+1), __ATOMIC_RELAXED, __HIP_MEMORY_SCOPE_AGENT);
      while (__hip_atomic_load(&flags[gg*8+tid], __ATOMIC_RELAXED, __HIP_MEMORY_SCOPE_AGENT) < (unsigned)(t+1))
        __builtin_amdgcn_s_sleep(1);
    }
    __syncthreads(); CBAR;                               // (6)
    // L: stage all 6 blocks' k2/v2 + nulls into LDS
    for (int idx = tid; idx < 1536; idx += 1024){
      const int j = idx/256, r = idx&255, b = r>>7, c = r&127;
      kvAll[b][j][c] = ldc(&xpub[xslot(par,gg,j,b) + c]);
    }
    if (tid < 12){
      const int j = tid>>1, b = tid&1;
      nullAll[b][j] = ldc(&xpub[xslot(par,gg,j,b) + 128]);
    }
    __syncthreads();                                     // (7)
    // N: att logits (i = n) + mask ranks
    if (tid < 48){
      const int b = tid/24, h = (tid/6)%4, j = tid%6;
      float lg = 0.f;
      #pragma unroll
      for (int kk=0; kk<16; ++kk)
        lg += kvqL[b][128 + h*16 + kk]*kvAll[b][j][h*16 + kk];
      attL[b][h][j] = lg*0.25f;
    }
    if (tid >= 48 && tid < 50){
      const int b = tid - 48;
      const float own = nullAll[b][n];
      int rank = 0;
      #pragma unroll
      for (int j=0;j<6;++j){
        const float v = nullAll[b][j];
        rank += (v > own || (v == own && j < n)) ? 1 : 0;
      }
      maskL[b] = (rank < 2) ? 0.f : 1.f;
    }
    __syncthreads();                                     // (8)
    if (tid < 8){
      const int b = tid>>2, h = tid&3;
      float mx = attL[b][h][0];
      #pragma unroll
      for (int j=1;j<6;++j) mx = fmaxf(mx, attL[b][h][j]);
      float e[6], sum = 0.f;
      #pragma unroll
      for (int j=0;j<6;++j){ e[j] = expf(attL[b][h][j]-mx); sum += e[j]; }
      const float inv = 1.f/sum;
      #pragma unroll
      for (int j=0;j<6;++j) attW[b][h][j] = e[j]*inv;
    }
    __syncthreads();                                     // (9)
    if (tid < 128){
      const int b = tid>>6, hv = tid&63, h = hv>>4, v = hv&15;
      float s2 = 0.f;
      #pragma unroll
      for (int j=0;j<6;++j) s2 += attW[b][h][j]*kvAll[b][j][64 + h*16 + v];
      commL[b][hv] = s2;
    }
    __syncthreads();                                     // (10)
    // Q: Wo + masked state update (8 threads per output dim)
    {
      #pragma unroll
      for (int b=0; b<2; ++b){
        float a = 0.f;
        #pragma unroll
        for (int j=0;j<4;++j) a += commL[b][okq*8+j]*wo0[j];
        #pragma unroll
        for (int j=0;j<4;++j) a += commL[b][okq*8+4+j]*wo1[j];
        a += __shfl_xor(a,1); a += __shfl_xor(a,2); a += __shfl_xor(a,4);
        if (okq == 0 && maskL[b] != 0.f){
          hL[b][od] = h0L[b][od] + a;
          cL[b][od] = cnL[b][od];
        }
      }
    }
    __syncthreads();                                     // (11)
    // R: HT (bf16) + final outputs
    if (tid < 256){
      const int b = tid>>7, d = tid&127;
      const float hv = hL[b][d];
      __hip_bfloat16 hb16 = __float2bfloat16(hv);
      HTx[(long)(t*32 + gg*2 + b)*768 + n*128 + d] = *reinterpret_cast<unsigned short*>(&hb16);
      if (t == TT-1){
        out_hx[(gg*2+b)*768 + n*128 + d] = hv;
        out_cx[(gg*2+b)*768 + n*128 + d] = cL[b][d];
      }
    }
  }
}

// ---------------- decoder: out = HT @ Wd^T + bd, bf16 MFMA ----------------
__global__ __launch_bounds__(256) void decoder_kernel(
    const unsigned short* __restrict__ A,   // [2048][768] bf16
    const unsigned short* __restrict__ Bw,  // [32000][768] bf16
    const float* __restrict__ bd,
    float* __restrict__ out)
{
  __shared__ unsigned short As[4096];  // [128][32]
  __shared__ unsigned short Bs[4096];  // [128][32]
  const int m0 = blockIdx.x*128, n0 = blockIdx.y*128;
  const int tid = threadIdx.x;
  const int wv = tid >> 6, lane = tid & 63;
  const int wm = wv >> 1, wn = wv & 1;
  const int r16 = lane & 15, krow = lane >> 4;

  f32x4 acc[4][4] = {};

  for (int k0 = 0; k0 < 768; k0 += 32){
    #pragma unroll
    for (int i=0; i<2; ++i){
      const int idx = i*256 + tid;
      const int row = idx >> 2, k8 = (idx & 3)*8;
      gload16(&A [(long)(m0+row)*768 + k0 + k8], (char*)As + i*4096 + wv*1024);
      gload16(&Bw[(long)(n0+row)*768 + k0 + k8], (char*)Bs + i*4096 + wv*1024);
    }
    __syncthreads();
    short8 af[4], bf[4];
    #pragma unroll
    for (int mi=0; mi<4; ++mi)
      af[mi] = *(const short8*)&As[(wm*64 + mi*16 + r16)*32 + krow*8];
    #pragma unroll
    for (int ni=0; ni<4; ++ni)
      bf[ni] = *(const short8*)&Bs[(wn*64 + ni*16 + r16)*32 + krow*8];
    #pragma unroll
    for (int mi=0; mi<4; ++mi)
      #pragma unroll
      for (int ni=0; ni<4; ++ni)
        acc[mi][ni] = __builtin_amdgcn_mfma_f32_16x16x32_bf16(af[mi], bf[ni], acc[mi][ni], 0, 0, 0);
    __syncthreads();
  }

  #pragma unroll
  for (int ni=0; ni<4; ++ni){
    const int col = n0 + wn*64 + ni*16 + r16;
    const float bv = bd[col];
    #pragma unroll
    for (int mi=0; mi<4; ++mi){
      const int rbase = m0 + wm*64 + mi*16 + krow*4;
      #pragma unroll
      for (int j=0; j<4; ++j)
        out[(size_t)(rbase + j)*NTOKC + col] = acc[mi][ni][j] + bv;
    }
  }
}

// ---------------- launch ----------------
extern "C" void kernel_launch(void* const* d_in, const int* in_sizes, int n_in,
                              void* d_out, int out_size, void* d_ws, size_t ws_size,
                              hipStream_t stream)
{
  (void)in_sizes; (void)n_in; (void)out_size; (void)ws_size;
  const float* x      = (const float*)d_in[0];
  const float* hx0    = (const float*)d_in[1];
  const float* cx0    = (const float*)d_in[2];
  const float* Wq_in  = (const float*)d_in[3];
  const float* Wk_in  = (const float*)d_in[4];
  const float* Wv_in  = (const float*)d_in[5];
  const float* Wih    = (const float*)d_in[6];
  const float* Whh    = (const float*)d_in[7];
  const float* b_lstm = (const float*)d_in[8];
  const float* Wq_c   = (const float*)d_in[9];
  const float* Wk_c   = (const float*)d_in[10];
  const float* Wv_c   = (const float*)d_in[11];
  const float* Wo_c   = (const float*)d_in[12];
  const float* Wd     = (const float*)d_in[13];
  const float* bd     = (const float*)d_in[14];

  char* ws = (char*)d_ws;
  unsigned int*  flg  = (unsigned int*)(ws + OFF_FLG);
  float*         xpub = (float*)(ws + OFF_XPUB);
  unsigned short* HTx = (unsigned short*)(ws + OFF_HTB);
  float*         K1b  = (float*)(ws + OFF_K1);
  float*         V1b  = (float*)(ws + OFF_V1);
  float*         Ub   = (float*)(ws + OFF_U);
  unsigned short* Wdb = (unsigned short*)(ws + OFF_WDB);

  float* out_dec = (float*)d_out;
  float* out_hx  = out_dec + (size_t)2048*NTOKC;
  float* out_cx  = out_hx + BB*NHIDC;

  // 1) reset flags + Wd -> bf16
  prep_kernel<<<2048, 256, 0, stream>>>(Wd, Wdb, flg);
  // 2) K1 = x @ Wk_in[1]   (2048 x 64, K=768)
  gemm_f32<4,4><<<dim3(32,1,1), 256, 0, stream>>>(x, NHIDC, Wk_in + 768*64, 64, 0,
                                                  K1b, 64, 0, 64, NHIDC);
  // 3) V1 = x @ Wv_in[1]   (2048 x 512, K=768)
  gemm_f32<4,4><<<dim3(32,8,1), 256, 0, stream>>>(x, NHIDC, Wv_in + 768*512, 512, 0,
                                                  V1b, 512, 0, 512, NHIDC);
  // 4) U[:, n, :] = V1 @ Wih[n]  (2048 x 512 per n, K=512)
  gemm_f32<8,8><<<dim3(16,4,6), 256, 0, stream>>>(V1b, 512, Wih, 512, (long)512*512,
                                                  Ub, 3072, 512, 512, 512);
  // 5) recurrence: 96 WGs x 1024 threads, writes HTx bf16 directly
  recurrent_kernel<<<96, 1024, 0, stream>>>(hx0, cx0, Wq_in, Whh, b_lstm,
                                            Wk_c, Wv_c, Wq_c, Wo_c,
                                            K1b, Ub, xpub, flg, HTx,
                                            out_hx, out_cx);
  // 6) decoder GEMM + bias
  decoder_kernel<<<dim3(16,250,1), 256, 0, stream>>>(HTx, Wdb, bd, out_dec);
}